// Round 19
// baseline (409.227 us; speedup 1.0000x reference)
//
#include <hip/hip_runtime.h>
#include <hip/hip_bf16.h>

#define NHD 16          // NH
#define NKVH 8          // NKV
#define HDIM 256        // HD
#define TSEQ 2048       // T
#define BATCH 2         // B

typedef unsigned int   u32;
typedef unsigned short u16;

typedef __attribute__((ext_vector_type(8))) short bf16x8;
typedef __attribute__((ext_vector_type(4))) float floatx4;

__device__ inline u32 cvt2bf(float lo, float hi) {
  u32 r;
  asm("v_cvt_pk_bf16_f32 %0, %1, %2" : "=v"(r) : "v"(lo), "v"(hi));
  return r;
}
__device__ inline u16 f2bf(float f) {
  union { float f; u32 i; } v; v.f = f;
  u32 r = v.i + 0x7fffu + ((v.i >> 16) & 1u);
  return (u16)(r >> 16);
}
__device__ inline float bf2f(u16 u) {
  union { u32 i; float f; } v; v.i = ((u32)u) << 16; return v.f;
}
__device__ inline float fexp2(float x) {
  float r; asm("v_exp_f32 %0, %1" : "=v"(r) : "v"(x)); return r;
}
__device__ inline float fsin(float x) {
  float r; asm("v_sin_f32 %0, %1" : "=v"(r) : "v"(x)); return r;
}
__device__ inline float fcos(float x) {
  float r; asm("v_cos_f32 %0, %1" : "=v"(r) : "v"(x)); return r;
}
__device__ inline float ffract(float x) {
  float r; asm("v_fract_f32 %0, %1" : "=v"(r) : "v"(x)); return r;
}

typedef const __attribute__((address_space(1))) u32* gptr_t;
typedef __attribute__((address_space(3))) u32* lptr_t;
__device__ inline void gl_lds16(const void* g, void* l) {
  __builtin_amdgcn_global_load_lds((gptr_t)g, (lptr_t)l, 16, 0, 0);
}

// ---------------------------------------------------------------------------
// Transpose+convert body: fp32 in[R][Cc] -> bf16 out[Cc][R], 64x64 tile (bx,by)
// ---------------------------------------------------------------------------
__device__ inline void tconv_body(const float* __restrict__ in,
                                  u16* __restrict__ out, int R, int Cc,
                                  int bx, int by, int tid) {
  __shared__ float tile[64][65];
  const int r0 = by * 64, c0 = bx * 64;
  const int tr = tid >> 4;
  const int tc = (tid & 15) * 4;
#pragma unroll
  for (int j = 0; j < 4; ++j) {
    float4 v = *(const float4*)(in + (size_t)(r0 + tr + j * 16) * Cc + c0 + tc);
    tile[tr + j * 16][tc + 0] = v.x;
    tile[tr + j * 16][tc + 1] = v.y;
    tile[tr + j * 16][tc + 2] = v.z;
    tile[tr + j * 16][tc + 3] = v.w;
  }
  __syncthreads();
#pragma unroll
  for (int j = 0; j < 4; ++j) {
    int c = tr + j * 16;
    u16 o[4];
#pragma unroll
    for (int i = 0; i < 4; ++i) o[i] = f2bf(tile[tc + i][c]);
    *(uint2*)(out + (size_t)(c0 + c) * R + r0 + tc) = *(const uint2*)o;
  }
}

__global__ __launch_bounds__(256) void tconv_k(
    const float* __restrict__ in, u16* __restrict__ out, int R, int Cc)
{
  tconv_body(in, out, R, Cc, blockIdx.x, blockIdx.y, threadIdx.x);
}

__global__ __launch_bounds__(256) void xconv_k(
    const float* __restrict__ in, u16* __restrict__ out)
{
  size_t i = (size_t)blockIdx.x * 256 + threadIdx.x;
  float4 a = *(const float4*)(in + i * 8);
  float4 b = *(const float4*)(in + i * 8 + 4);
  uint4 o;
  o.x = cvt2bf(a.x, a.y); o.y = cvt2bf(a.z, a.w);
  o.z = cvt2bf(b.x, b.y); o.w = cvt2bf(b.z, b.w);
  *(uint4*)(out + i * 8) = o;
}

// ---------------------------------------------------------------------------
// Merged prep: X cvt + Wq^T + Wk^T + Wv^T (+ Wo^T when grid = 10240).
// blocks [0,4096) X; [4096,6144) Wq; [6144,7168) Wk; [7168,8192) Wv;
// [8192,10240) Wo.
// ---------------------------------------------------------------------------
__global__ __launch_bounds__(256) void prep_k(
    const float* __restrict__ X,  const float* __restrict__ Wq,
    const float* __restrict__ Wk, const float* __restrict__ Wv,
    const float* __restrict__ Wo,
    u16* __restrict__ XB, u16* __restrict__ WqT, u16* __restrict__ WkvT,
    u16* __restrict__ WoT)
{
  const int bid = blockIdx.x, tid = threadIdx.x;
  if (bid < 4096) {
    size_t i = (size_t)bid * 256 + tid;
    float4 a = *(const float4*)(X + i * 8);
    float4 b = *(const float4*)(X + i * 8 + 4);
    uint4 o;
    o.x = cvt2bf(a.x, a.y); o.y = cvt2bf(a.z, a.w);
    o.z = cvt2bf(b.x, b.y); o.w = cvt2bf(b.z, b.w);
    *(uint4*)(XB + i * 8) = o;
  } else if (bid < 6144) {
    int idx = bid - 4096;
    tconv_body(Wq, WqT, 2048, 4096, idx & 63, idx >> 6, tid);
  } else if (bid < 7168) {
    int idx = bid - 6144;
    tconv_body(Wk, WkvT, 2048, 2048, idx & 31, idx >> 5, tid);
  } else if (bid < 8192) {
    int idx = bid - 7168;
    tconv_body(Wv, WkvT + (size_t)2048 * 2048, 2048, 2048, idx & 31, idx >> 5, tid);
  } else {
    int idx = bid - 8192;
    tconv_body(Wo, WoT, 4096, 2048, idx & 31, idx >> 5, tid);
  }
}

// ---------------------------------------------------------------------------
// R5-proven 2-phase GEMM + FUSED ROPE EPILOGUE (R15, proven).
// ---------------------------------------------------------------------------
template<int EPI, int BM>
__global__ __launch_bounds__(512, 2) void gemm256_k(
    const u16* __restrict__ Ab, const u16* __restrict__ BTp,
    void* __restrict__ Op, int M, int N, int K)
{
  constexpr int NI = BM / 32;
  constexpr int AI = BM / 64;
  __shared__ u16 LA[2][BM * 64];
  __shared__ u16 LB[2][256 * 64];
  const int t = threadIdx.x;
  const int lane = t & 63, wave = t >> 6;
  const int lg = lane >> 4, l15 = lane & 15;
  const int wm = wave >> 2, wn = wave & 3;
  const int mtiles = M / BM;
  const int mt = (int)blockIdx.x % mtiles, nt = (int)blockIdx.x / mtiles;
  const int m0 = mt * BM, n0 = nt << 8;

  const int arow = wave * (BM / 8) + (lane >> 3);
  const int ska  = ((lane & 7) ^ (arow & 7)) << 3;
  const int brow = wave * 32 + (lane >> 3);
  const int skb  = ((lane & 7) ^ (brow & 7)) << 3;
  const u16* Ag = Ab  + (size_t)(m0 + arow) * K + ska;
  const u16* Bg = BTp + (size_t)(n0 + brow) * K + skb;

  auto STAGE = [&](int k0, int sel) {
#pragma unroll
    for (int q = 0; q < AI; ++q)
      gl_lds16(Ag + k0 + (size_t)q * 8 * K, &LA[sel][(wave * (BM / 8) + q * 8) * 64]);
#pragma unroll
    for (int q = 0; q < 4; ++q)
      gl_lds16(Bg + k0 + (size_t)q * 8 * K, &LB[sel][(wave * 32 + q * 8) * 64]);
  };

  floatx4 acc[NI][4];
#pragma unroll
  for (int i = 0; i < NI; ++i)
#pragma unroll
    for (int j = 0; j < 4; ++j) acc[i][j] = (floatx4){0.f, 0.f, 0.f, 0.f};

  STAGE(0, 0);
  const int KT = K >> 6;
  for (int kt = 0; kt < KT; ++kt) {
    const int sel = kt & 1;
    if (kt + 1 < KT) {
      STAGE((kt + 1) << 6, sel ^ 1);
      if constexpr (BM == 256) asm volatile("s_waitcnt vmcnt(8)" ::: "memory");
      else                     asm volatile("s_waitcnt vmcnt(6)" ::: "memory");
    } else {
      asm volatile("s_waitcnt vmcnt(0)" ::: "memory");
    }
    __builtin_amdgcn_s_barrier();
    __builtin_amdgcn_sched_barrier(0);
    __builtin_amdgcn_s_setprio(1);
#pragma unroll
    for (int ks = 0; ks < 2; ++ks) {
      const int c = (ks << 2) + lg;
      bf16x8 bfv[4];
#pragma unroll
      for (int j = 0; j < 4; ++j) {
        int row = (EPI == 0) ? (wn * 64 + (j << 4) + l15)
                             : (wn * 32 + ((j & 1) << 4) + ((j >> 1) << 7) + l15);
        bfv[j] = *(const bf16x8*)(&LB[sel][row * 64 + ((c ^ (row & 7)) << 3)]);
      }
#pragma unroll
      for (int i = 0; i < NI; ++i) {
        int row = wm * (BM / 2) + (i << 4) + l15;
        bf16x8 af = *(const bf16x8*)(&LA[sel][row * 64 + ((c ^ (row & 7)) << 3)]);
#pragma unroll
        for (int j = 0; j < 4; ++j)
          acc[i][j] = __builtin_amdgcn_mfma_f32_16x16x32_bf16(af, bfv[j], acc[i][j], 0, 0, 0);
      }
    }
    __builtin_amdgcn_s_setprio(0);
    __builtin_amdgcn_s_barrier();
  }

  if constexpr (EPI == 0) {
#pragma unroll
    for (int i = 0; i < NI; ++i)
#pragma unroll
      for (int j = 0; j < 4; ++j)
#pragma unroll
        for (int r = 0; r < 4; ++r) {
          int m = m0 + wm * (BM / 2) + (i << 4) + (lg << 2) + r;
          int n = n0 + wn * 64 + (j << 4) + l15;
          ((float*)Op)[(size_t)m * N + n] = acc[i][j][r];
        }
  } else {
    float invf2[2];
#pragma unroll
    for (int j = 0; j < 2; ++j) {
      int col = wn * 32 + (j << 4) + l15;
      invf2[j] = fexp2(fmaf(-(float)col, 0.103810253f, -2.651496129f));
    }
#pragma unroll
    for (int i = 0; i < NI; ++i) {
#pragma unroll
      for (int j = 0; j < 2; ++j) {
        int col = wn * 32 + (j << 4) + l15;
        int n_lo = n0 + col;
#pragma unroll
        for (int r = 0; r < 4; ++r) {
          int m = m0 + wm * (BM / 2) + (i << 4) + (lg << 2) + r;
          int bb = m >> 11, tt = m & 2047;
          float vlo = acc[i][j][r], vhi = acc[i][j + 2][r];
          if (EPI == 1 || n_lo < 2048) {
            float rev = ffract((float)tt * invf2[j]);
            float sn = fsin(rev), cs = fcos(rev);
            float olo = vlo * cs - vhi * sn;
            float ohi = vhi * cs + vlo * sn;
            vlo = olo; vhi = ohi;
          }
          if (EPI == 1) {
            int h = n_lo >> 8;
            u16* dst = (u16*)Op + (((size_t)bb * NHD + h) * TSEQ + tt) * HDIM + col;
            dst[0]   = f2bf(vlo);
            dst[128] = f2bf(vhi);
          } else {
            if (n_lo < 2048) {
              int h = n_lo >> 8;
              u16* dst = (u16*)Op + (((size_t)bb * NKVH + h) * TSEQ + tt) * HDIM + col;
              dst[0]   = f2bf(vlo);
              dst[128] = f2bf(vhi);
            } else {
              int n2 = n_lo - 2048;
              int h = n2 >> 8;
              u16* dst = (u16*)Op + 8388608u +
                         (((size_t)bb * NKVH + h) * HDIM + col) * TSEQ + tt;
              dst[0] = f2bf(vlo);
              dst[(size_t)128 * TSEQ] = f2bf(vhi);
            }
          }
        }
      }
    }
  }
}

// ---------------------------------------------------------------------------
// Causal flash attention: GQA-pair block (512 thr, waves 0-3 head 2hkv,
// 4-7 head 2hkv+1, shared K/V) + BOTH K and V double-buffered -> 2 barriers
// per iter.  Iter st: stage K(st+1)+V(st+1) into sel^1 (4 gl_lds/thread);
// vmcnt(4) drains tile st's 4 (issued 1 iter earlier, latency hidden);
// barrier; QK + PV on sel; barrier.  Tail vmcnt(0).  LDS 72.5 KB -> 2
// blocks/CU = 16 waves.  Grid: x=(hkv,b)=16, y=qt desc (LPT).
// ---------------------------------------------------------------------------
__global__ __launch_bounds__(512, 2) void attn_k(
    const u16* __restrict__ Q, const u16* __restrict__ Kb,
    const u16* __restrict__ Vt, u16* __restrict__ Y)
{
  __shared__ u16 Ks2[2][32 * 256];   // 32 KB, [s][d] 512B rows, src-swizzled
  __shared__ u16 Vs2[2][256 * 32];   // 32 KB, [d][s] 64B rows, src-swizzled
  __shared__ u16 Ps[8 * 16 * 32];    // 8 KB, per-wave [q16][s32]
  __shared__ float Ls[8][16];
  const int t = threadIdx.x, lane = t & 63, w = t >> 6;   // w in 0..7
  const int lg = lane >> 4, l15 = lane & 15;
  const int hq = w >> 2, wq = w & 3;                      // head-half, q-group
  const int qt = 31 - (int)blockIdx.y;                    // big blocks first
  const int hkv = (int)blockIdx.x >> 1, b = (int)blockIdx.x & 1;
  const int h = 2 * hkv + hq;

  const u16* Kg = Kb + ((size_t)(b * NKVH + hkv)) * TSEQ * HDIM;  // [s][d]
  const u16* Vg = Vt + ((size_t)(b * NKVH + hkv)) * HDIM * TSEQ;  // [d][s]

  int koff[2], voff[2];
#pragma unroll
  for (int q = 0; q < 2; ++q) {
    int krow = w * 4 + q * 2 + (lane >> 5);
    int kcc  = lane & 31;
    koff[q] = krow * 256 + ((kcc ^ (krow & 7)) << 3);
    int vd  = w * 32 + q * 16 + (lane >> 2);
    voff[q] = vd * TSEQ + (((lane & 3) ^ ((vd >> 2) & 3)) << 3);
  }

  auto STAGE = [&](int st, int sel) {
    const u16* kbase = Kg + (size_t)st * (32 * 256);
    const u16* vbase = Vg + st * 32;
#pragma unroll
    for (int q = 0; q < 2; ++q)
      gl_lds16(kbase + koff[q], &Ks2[sel][(w * 4 + q * 2) * 256]);
#pragma unroll
    for (int q = 0; q < 2; ++q)
      gl_lds16(vbase + voff[q], &Vs2[sel][(w * 32 + q * 16) * 32]);
  };

  const u16* Qg = Q + (((size_t)(b * NHD + h)) * TSEQ + qt * 64 + wq * 16 + l15) * HDIM;
  bf16x8 qf[8];
#pragma unroll
  for (int ks = 0; ks < 8; ++ks) qf[ks] = *(const bf16x8*)(Qg + ks * 32 + lg * 8);

  floatx4 accY[16];
#pragma unroll
  for (int i = 0; i < 16; ++i) accY[i] = (floatx4){0.f, 0.f, 0.f, 0.f};
  float rsum = 0.f;

  const int qglob = qt * 64 + wq * 16 + l15;
  const int qmaxw = qt * 64 + wq * 16 + 15;
  const int nst = 2 * qt + 2;
  const int fps = (l15 ^ (l15 >> 2)) & 3;      // Ps bank-spread term

  STAGE(0, 0);
  for (int st = 0; st < nst; ++st) {
    const int sel = st & 1;
    if (st + 1 < nst) {
      STAGE(st + 1, sel ^ 1);
      asm volatile("s_waitcnt vmcnt(4)" ::: "memory");   // tile st landed
    } else {
      asm volatile("s_waitcnt vmcnt(0)" ::: "memory");
    }
    __builtin_amdgcn_s_barrier();                        // K+V visible
    __builtin_amdgcn_sched_barrier(0);

    if (st * 32 <= qmaxw) {
      __builtin_amdgcn_s_setprio(1);
      // --- QK^T (swapped) + softcap + causal + P write ---
#pragma unroll
      for (int stile = 0; stile < 2; ++stile) {
        floatx4 sa0 = (floatx4){0.f, 0.f, 0.f, 0.f};
        floatx4 sa1 = (floatx4){0.f, 0.f, 0.f, 0.f};
#pragma unroll
        for (int ks = 0; ks < 8; ++ks) {
          int row = (stile << 4) + l15;
          int c = (ks << 2) + lg;
          bf16x8 kf = *(const bf16x8*)((const char*)Ks2[sel] +
                        row * 512 + ((c ^ (row & 7)) << 4));
          if (ks & 1)
            sa1 = __builtin_amdgcn_mfma_f32_16x16x32_bf16(kf, qf[ks], sa1, 0, 0, 0);
          else
            sa0 = __builtin_amdgcn_mfma_f32_16x16x32_bf16(kf, qf[ks], sa0, 0, 0, 0);
        }
        int sbase = st * 32 + (stile << 4) + (lg << 2);
        float p[4];
#pragma unroll
        for (int r = 0; r < 4; ++r) {
          float s = sa0[r] + sa1[r];
          float tt = fmaf(s * s, -5.2083333e-7f, 1.0f);   // 1 - z^2/7500
          float pv = fexp2(s * 0.0901684403f * tt);       // exp2(cap*log2e)
          pv = (sbase + r <= qglob) ? pv : 0.0f;
          p[r] = pv;
          rsum += pv;
        }
        uint2 pw;
        pw.x = cvt2bf(p[0], p[1]);
        pw.y = cvt2bf(p[2], p[3]);
        int o = (stile << 5) + (lg << 3);
        int gran = (o >> 4) ^ fps;
        *(uint2*)((char*)Ps + (w << 10) + l15 * 64 + (gran << 4) + (o & 15)) = pw;
      }
      // --- PV ---
      {
        bf16x8 pf = *(const bf16x8*)((const char*)Ps + (w << 10) + l15 * 64 +
                      ((lg ^ fps) << 4));
#pragma unroll
        for (int dt = 0; dt < 16; ++dt) {
          int row = (dt << 4) + l15;
          bf16x8 vf = *(const bf16x8*)((const char*)Vs2[sel] +
                        row * 64 + ((lg ^ ((row >> 2) & 3)) << 4));
          accY[dt] = __builtin_amdgcn_mfma_f32_16x16x32_bf16(pf, vf, accY[dt], 0, 0, 0);
        }
      }
      __builtin_amdgcn_s_setprio(0);
    }
    __builtin_amdgcn_s_barrier();   // readers of sel done before overwrite
  }

  rsum += __shfl_xor(rsum, 16);
  rsum += __shfl_xor(rsum, 32);
  if (lane < 16) Ls[w][l15] = rsum;
  __syncthreads();
  float inv[4];
#pragma unroll
  for (int r = 0; r < 4; ++r) inv[r] = 1.0f / Ls[w][(lg << 2) + r];

  u16* Yg = Y + ((size_t)(b * TSEQ + qt * 64 + wq * 16)) * (NHD * HDIM) + h * HDIM;
#pragma unroll
  for (int dt = 0; dt < 16; ++dt)
#pragma unroll
    for (int r = 0; r < 4; ++r)
      Yg[(size_t)((lg << 2) + r) * (NHD * HDIM) + (dt << 4) + l15] =
          f2bf(accY[dt][r] * inv[r]);
}

// ---------------------------------------------------------------------------
extern "C" void kernel_launch(void* const* d_in, const int* in_sizes, int n_in,
                              void* d_out, int out_size, void* d_ws, size_t ws_size,
                              hipStream_t stream) {
  const float* X  = (const float*)d_in[0];
  const float* Wq = (const float*)d_in[1];
  const float* Wk = (const float*)d_in[2];
  const float* Wv = (const float*)d_in[3];
  const float* Wo = (const float*)d_in[4];
  float* out = (float*)d_out;

  u16* ws = (u16*)d_ws;
  dim3 blk(256);

  if (ws_size >= (size_t)134217728) {
    // extended layout: Wo^T folded into prep (5 launches total)
    u16* XB   = ws;                  // 8,388,608
    u16* WqT  = ws + 8388608;        // 8,388,608
    u16* WkvT = ws + 16777216;       // 8,388,608
    u16* Qb   = ws + 25165824;       // 16,777,216
    u16* KVb  = ws + 41943040;       // 16,777,216
    u16* WoT  = ws + 58720256;       // 8,388,608
    u16* Yb   = ws;                  // over XB+WqT (dead by then)

    prep_k<<<dim3(10240), blk, 0, stream>>>(X, Wq, Wk, Wv, Wo, XB, WqT, WkvT, WoT);
    gemm256_k<1, 256><<<dim3(256), dim3(512), 0, stream>>>(XB, WqT,  Qb,  4096, 4096, 2048);
    gemm256_k<3, 256><<<dim3(256), dim3(512), 0, stream>>>(XB, WkvT, KVb, 4096, 4096, 2048);
    attn_k<<<dim3(16, 32), dim3(512), 0, stream>>>(Qb, KVb, KVb + 8388608, Yb);
    gemm256_k<0, 128><<<dim3(256), dim3(512), 0, stream>>>(Yb, WoT, out, 4096, 2048, 4096);
  } else if (ws_size >= (size_t)117440512) {
    u16* XB   = ws;                  // 8,388,608
    u16* WqT  = ws + 8388608;        // 8,388,608
    u16* WkvT = ws + 16777216;       // 8,388,608
    u16* Qb   = ws + 25165824;       // 16,777,216
    u16* KVb  = ws + 41943040;       // 16,777,216
    u16* Yb   = ws;                  // over XB+WqT (dead by then)
    u16* WoT  = ws + 25165824;       // over Qb (dead after attn)

    prep_k<<<dim3(8192), blk, 0, stream>>>(X, Wq, Wk, Wv, Wo, XB, WqT, WkvT, WkvT);
    gemm256_k<1, 256><<<dim3(256), dim3(512), 0, stream>>>(XB, WqT,  Qb,  4096, 4096, 2048);
    gemm256_k<3, 256><<<dim3(256), dim3(512), 0, stream>>>(XB, WkvT, KVb, 4096, 4096, 2048);
    attn_k<<<dim3(16, 32), dim3(512), 0, stream>>>(Qb, KVb, KVb + 8388608, Yb);
    tconv_k<<<dim3(32, 64), blk, 0, stream>>>(Wo, WoT, 4096, 2048);
    gemm256_k<0, 128><<<dim3(256), dim3(512), 0, stream>>>(Yb, WoT, out, 4096, 2048, 4096);
  } else {
    u16* XB   = ws;                  // 8,388,608
    u16* WT   = ws + 8388608;        // 8,388,608 (WqT then WkvT, sequential)
    u16* Qb   = ws + 16777216;       // 16,777,216
    u16* KVb  = ws + 33554432;       // 16,777,216
    u16* Yb   = ws;                  // over XB+WT
    u16* WoT  = ws + 16777216;       // over Qb

    xconv_k<<<dim3(4096), blk, 0, stream>>>(X, XB);
    tconv_k<<<dim3(64, 32), blk, 0, stream>>>(Wq, WT, 2048, 4096);
    gemm256_k<1, 256><<<dim3(256), dim3(512), 0, stream>>>(XB, WT, Qb, 4096, 4096, 2048);
    tconv_k<<<dim3(32, 32), blk, 0, stream>>>(Wk, WT, 2048, 2048);
    tconv_k<<<dim3(32, 32), blk, 0, stream>>>(Wv, WT + (size_t)2048 * 2048, 2048, 2048);
    gemm256_k<3, 256><<<dim3(256), dim3(512), 0, stream>>>(XB, WT, KVb, 4096, 4096, 2048);
    attn_k<<<dim3(16, 32), dim3(512), 0, stream>>>(Qb, KVb, KVb + 8388608, Yb);
    tconv_k<<<dim3(32, 64), blk, 0, stream>>>(Wo, WoT, 4096, 2048);
    gemm256_k<0, 128><<<dim3(256), dim3(512), 0, stream>>>(Yb, WoT, out, 4096, 2048, 4096);
  }
}

// Round 20
// 393.359 us; speedup vs baseline: 1.0403x; 1.0403x over previous
//
#include <hip/hip_runtime.h>
#include <hip/hip_bf16.h>

#define NHD 16          // NH
#define NKVH 8          // NKV
#define HDIM 256        // HD
#define TSEQ 2048       // T
#define BATCH 2         // B

typedef unsigned int   u32;
typedef unsigned short u16;

typedef __attribute__((ext_vector_type(8))) short bf16x8;
typedef __attribute__((ext_vector_type(4))) float floatx4;

__device__ inline u32 cvt2bf(float lo, float hi) {
  u32 r;
  asm("v_cvt_pk_bf16_f32 %0, %1, %2" : "=v"(r) : "v"(lo), "v"(hi));
  return r;
}
__device__ inline u16 f2bf(float f) {
  union { float f; u32 i; } v; v.f = f;
  u32 r = v.i + 0x7fffu + ((v.i >> 16) & 1u);
  return (u16)(r >> 16);
}
__device__ inline float bf2f(u16 u) {
  union { u32 i; float f; } v; v.i = ((u32)u) << 16; return v.f;
}
__device__ inline float fexp2(float x) {
  float r; asm("v_exp_f32 %0, %1" : "=v"(r) : "v"(x)); return r;
}
__device__ inline float fsin(float x) {
  float r; asm("v_sin_f32 %0, %1" : "=v"(r) : "v"(x)); return r;
}
__device__ inline float fcos(float x) {
  float r; asm("v_cos_f32 %0, %1" : "=v"(r) : "v"(x)); return r;
}
__device__ inline float ffract(float x) {
  float r; asm("v_fract_f32 %0, %1" : "=v"(r) : "v"(x)); return r;
}

typedef const __attribute__((address_space(1))) u32* gptr_t;
typedef __attribute__((address_space(3))) u32* lptr_t;
__device__ inline void gl_lds16(const void* g, void* l) {
  __builtin_amdgcn_global_load_lds((gptr_t)g, (lptr_t)l, 16, 0, 0);
}

// ---------------------------------------------------------------------------
// Transpose+convert body: fp32 in[R][Cc] -> bf16 out[Cc][R], 64x64 tile (bx,by)
// ---------------------------------------------------------------------------
__device__ inline void tconv_body(const float* __restrict__ in,
                                  u16* __restrict__ out, int R, int Cc,
                                  int bx, int by, int tid) {
  __shared__ float tile[64][65];
  const int r0 = by * 64, c0 = bx * 64;
  const int tr = tid >> 4;
  const int tc = (tid & 15) * 4;
#pragma unroll
  for (int j = 0; j < 4; ++j) {
    float4 v = *(const float4*)(in + (size_t)(r0 + tr + j * 16) * Cc + c0 + tc);
    tile[tr + j * 16][tc + 0] = v.x;
    tile[tr + j * 16][tc + 1] = v.y;
    tile[tr + j * 16][tc + 2] = v.z;
    tile[tr + j * 16][tc + 3] = v.w;
  }
  __syncthreads();
#pragma unroll
  for (int j = 0; j < 4; ++j) {
    int c = tr + j * 16;
    u16 o[4];
#pragma unroll
    for (int i = 0; i < 4; ++i) o[i] = f2bf(tile[tc + i][c]);
    *(uint2*)(out + (size_t)(c0 + c) * R + r0 + tc) = *(const uint2*)o;
  }
}

__global__ __launch_bounds__(256) void tconv_k(
    const float* __restrict__ in, u16* __restrict__ out, int R, int Cc)
{
  tconv_body(in, out, R, Cc, blockIdx.x, blockIdx.y, threadIdx.x);
}

__global__ __launch_bounds__(256) void xconv_k(
    const float* __restrict__ in, u16* __restrict__ out)
{
  size_t i = (size_t)blockIdx.x * 256 + threadIdx.x;
  float4 a = *(const float4*)(in + i * 8);
  float4 b = *(const float4*)(in + i * 8 + 4);
  uint4 o;
  o.x = cvt2bf(a.x, a.y); o.y = cvt2bf(a.z, a.w);
  o.z = cvt2bf(b.x, b.y); o.w = cvt2bf(b.z, b.w);
  *(uint4*)(out + i * 8) = o;
}

// ---------------------------------------------------------------------------
// Merged prep: X cvt + Wq^T + Wk^T + Wv^T (+ Wo^T when grid = 10240).
// ---------------------------------------------------------------------------
__global__ __launch_bounds__(256) void prep_k(
    const float* __restrict__ X,  const float* __restrict__ Wq,
    const float* __restrict__ Wk, const float* __restrict__ Wv,
    const float* __restrict__ Wo,
    u16* __restrict__ XB, u16* __restrict__ WqT, u16* __restrict__ WkvT,
    u16* __restrict__ WoT)
{
  const int bid = blockIdx.x, tid = threadIdx.x;
  if (bid < 4096) {
    size_t i = (size_t)bid * 256 + tid;
    float4 a = *(const float4*)(X + i * 8);
    float4 b = *(const float4*)(X + i * 8 + 4);
    uint4 o;
    o.x = cvt2bf(a.x, a.y); o.y = cvt2bf(a.z, a.w);
    o.z = cvt2bf(b.x, b.y); o.w = cvt2bf(b.z, b.w);
    *(uint4*)(XB + i * 8) = o;
  } else if (bid < 6144) {
    int idx = bid - 4096;
    tconv_body(Wq, WqT, 2048, 4096, idx & 63, idx >> 6, tid);
  } else if (bid < 7168) {
    int idx = bid - 6144;
    tconv_body(Wk, WkvT, 2048, 2048, idx & 31, idx >> 5, tid);
  } else if (bid < 8192) {
    int idx = bid - 7168;
    tconv_body(Wv, WkvT + (size_t)2048 * 2048, 2048, 2048, idx & 31, idx >> 5, tid);
  } else {
    int idx = bid - 8192;
    tconv_body(Wo, WoT, 4096, 2048, idx & 31, idx >> 5, tid);
  }
}

// ---------------------------------------------------------------------------
// R5-proven 2-phase GEMM + FUSED ROPE EPILOGUE (R15, proven).
// ---------------------------------------------------------------------------
template<int EPI, int BM>
__global__ __launch_bounds__(512, 2) void gemm256_k(
    const u16* __restrict__ Ab, const u16* __restrict__ BTp,
    void* __restrict__ Op, int M, int N, int K)
{
  constexpr int NI = BM / 32;
  constexpr int AI = BM / 64;
  __shared__ u16 LA[2][BM * 64];
  __shared__ u16 LB[2][256 * 64];
  const int t = threadIdx.x;
  const int lane = t & 63, wave = t >> 6;
  const int lg = lane >> 4, l15 = lane & 15;
  const int wm = wave >> 2, wn = wave & 3;
  const int mtiles = M / BM;
  const int mt = (int)blockIdx.x % mtiles, nt = (int)blockIdx.x / mtiles;
  const int m0 = mt * BM, n0 = nt << 8;

  const int arow = wave * (BM / 8) + (lane >> 3);
  const int ska  = ((lane & 7) ^ (arow & 7)) << 3;
  const int brow = wave * 32 + (lane >> 3);
  const int skb  = ((lane & 7) ^ (brow & 7)) << 3;
  const u16* Ag = Ab  + (size_t)(m0 + arow) * K + ska;
  const u16* Bg = BTp + (size_t)(n0 + brow) * K + skb;

  auto STAGE = [&](int k0, int sel) {
#pragma unroll
    for (int q = 0; q < AI; ++q)
      gl_lds16(Ag + k0 + (size_t)q * 8 * K, &LA[sel][(wave * (BM / 8) + q * 8) * 64]);
#pragma unroll
    for (int q = 0; q < 4; ++q)
      gl_lds16(Bg + k0 + (size_t)q * 8 * K, &LB[sel][(wave * 32 + q * 8) * 64]);
  };

  floatx4 acc[NI][4];
#pragma unroll
  for (int i = 0; i < NI; ++i)
#pragma unroll
    for (int j = 0; j < 4; ++j) acc[i][j] = (floatx4){0.f, 0.f, 0.f, 0.f};

  STAGE(0, 0);
  const int KT = K >> 6;
  for (int kt = 0; kt < KT; ++kt) {
    const int sel = kt & 1;
    if (kt + 1 < KT) {
      STAGE((kt + 1) << 6, sel ^ 1);
      if constexpr (BM == 256) asm volatile("s_waitcnt vmcnt(8)" ::: "memory");
      else                     asm volatile("s_waitcnt vmcnt(6)" ::: "memory");
    } else {
      asm volatile("s_waitcnt vmcnt(0)" ::: "memory");
    }
    __builtin_amdgcn_s_barrier();
    __builtin_amdgcn_sched_barrier(0);
    __builtin_amdgcn_s_setprio(1);
#pragma unroll
    for (int ks = 0; ks < 2; ++ks) {
      const int c = (ks << 2) + lg;
      bf16x8 bfv[4];
#pragma unroll
      for (int j = 0; j < 4; ++j) {
        int row = (EPI == 0) ? (wn * 64 + (j << 4) + l15)
                             : (wn * 32 + ((j & 1) << 4) + ((j >> 1) << 7) + l15);
        bfv[j] = *(const bf16x8*)(&LB[sel][row * 64 + ((c ^ (row & 7)) << 3)]);
      }
#pragma unroll
      for (int i = 0; i < NI; ++i) {
        int row = wm * (BM / 2) + (i << 4) + l15;
        bf16x8 af = *(const bf16x8*)(&LA[sel][row * 64 + ((c ^ (row & 7)) << 3)]);
#pragma unroll
        for (int j = 0; j < 4; ++j)
          acc[i][j] = __builtin_amdgcn_mfma_f32_16x16x32_bf16(af, bfv[j], acc[i][j], 0, 0, 0);
      }
    }
    __builtin_amdgcn_s_setprio(0);
    __builtin_amdgcn_s_barrier();
  }

  if constexpr (EPI == 0) {
#pragma unroll
    for (int i = 0; i < NI; ++i)
#pragma unroll
      for (int j = 0; j < 4; ++j)
#pragma unroll
        for (int r = 0; r < 4; ++r) {
          int m = m0 + wm * (BM / 2) + (i << 4) + (lg << 2) + r;
          int n = n0 + wn * 64 + (j << 4) + l15;
          ((float*)Op)[(size_t)m * N + n] = acc[i][j][r];
        }
  } else {
    float invf2[2];
#pragma unroll
    for (int j = 0; j < 2; ++j) {
      int col = wn * 32 + (j << 4) + l15;
      invf2[j] = fexp2(fmaf(-(float)col, 0.103810253f, -2.651496129f));
    }
#pragma unroll
    for (int i = 0; i < NI; ++i) {
#pragma unroll
      for (int j = 0; j < 2; ++j) {
        int col = wn * 32 + (j << 4) + l15;
        int n_lo = n0 + col;
#pragma unroll
        for (int r = 0; r < 4; ++r) {
          int m = m0 + wm * (BM / 2) + (i << 4) + (lg << 2) + r;
          int bb = m >> 11, tt = m & 2047;
          float vlo = acc[i][j][r], vhi = acc[i][j + 2][r];
          if (EPI == 1 || n_lo < 2048) {
            float rev = ffract((float)tt * invf2[j]);
            float sn = fsin(rev), cs = fcos(rev);
            float olo = vlo * cs - vhi * sn;
            float ohi = vhi * cs + vlo * sn;
            vlo = olo; vhi = ohi;
          }
          if (EPI == 1) {
            int h = n_lo >> 8;
            u16* dst = (u16*)Op + (((size_t)bb * NHD + h) * TSEQ + tt) * HDIM + col;
            dst[0]   = f2bf(vlo);
            dst[128] = f2bf(vhi);
          } else {
            if (n_lo < 2048) {
              int h = n_lo >> 8;
              u16* dst = (u16*)Op + (((size_t)bb * NKVH + h) * TSEQ + tt) * HDIM + col;
              dst[0]   = f2bf(vlo);
              dst[128] = f2bf(vhi);
            } else {
              int n2 = n_lo - 2048;
              int h = n2 >> 8;
              u16* dst = (u16*)Op + 8388608u +
                         (((size_t)bb * NKVH + h) * HDIM + col) * TSEQ + tt;
              dst[0] = f2bf(vlo);
              dst[(size_t)128 * TSEQ] = f2bf(vhi);
            }
          }
        }
      }
    }
  }
}

// ---------------------------------------------------------------------------
// Causal flash attention (R18 winner, verbatim): GQA-pair block (512 thr,
// waves 0-3 head 2hkv, 4-7 head 2hkv+1, shared K/V), K dbuf + V single via
// gl_lds, 2 K + 2 V chunks per thread.
// Iter: STAGE_V(st); STAGE_K(st+1); vmcnt(4) -> bar -> QK -> vmcnt(2) ->
// bar -> PV -> bar.  Tail: 2/0.  LDS 56.5 KB -> 2 blocks/CU = 16 waves.
// Grid: x=(hkv,b)=16, y=qt descending (LPT).
// ---------------------------------------------------------------------------
__global__ __launch_bounds__(512, 2) void attn_k(
    const u16* __restrict__ Q, const u16* __restrict__ Kb,
    const u16* __restrict__ Vt, u16* __restrict__ Y)
{
  __shared__ u16 Ks2[2][32 * 256];   // 32 KB, [s][d] 512B rows, src-swizzled
  __shared__ u16 Vs[256 * 32];       // 16 KB, [d][s] 64B rows, src-swizzled
  __shared__ u16 Ps[8 * 16 * 32];    // 8 KB, per-wave [q16][s32]
  __shared__ float Ls[8][16];
  const int t = threadIdx.x, lane = t & 63, w = t >> 6;   // w in 0..7
  const int lg = lane >> 4, l15 = lane & 15;
  const int hq = w >> 2, wq = w & 3;                      // head-half, q-group
  const int qt = 31 - (int)blockIdx.y;                    // big blocks first
  const int hkv = (int)blockIdx.x >> 1, b = (int)blockIdx.x & 1;
  const int h = 2 * hkv + hq;

  const u16* Kg = Kb + ((size_t)(b * NKVH + hkv)) * TSEQ * HDIM;  // [s][d]
  const u16* Vg = Vt + ((size_t)(b * NKVH + hkv)) * HDIM * TSEQ;  // [d][s]

  int koff[2], voff[2];
#pragma unroll
  for (int q = 0; q < 2; ++q) {
    int krow = w * 4 + q * 2 + (lane >> 5);
    int kcc  = lane & 31;
    koff[q] = krow * 256 + ((kcc ^ (krow & 7)) << 3);
    int vd  = w * 32 + q * 16 + (lane >> 2);
    voff[q] = vd * TSEQ + (((lane & 3) ^ ((vd >> 2) & 3)) << 3);
  }

  auto STAGE_K = [&](int st, int sel) {
    const u16* kbase = Kg + (size_t)st * (32 * 256);
#pragma unroll
    for (int q = 0; q < 2; ++q)
      gl_lds16(kbase + koff[q], &Ks2[sel][(w * 4 + q * 2) * 256]);
  };
  auto STAGE_V = [&](int st) {
    const u16* vbase = Vg + st * 32;
#pragma unroll
    for (int q = 0; q < 2; ++q)
      gl_lds16(vbase + voff[q], &Vs[(w * 32 + q * 16) * 32]);
  };

  const u16* Qg = Q + (((size_t)(b * NHD + h)) * TSEQ + qt * 64 + wq * 16 + l15) * HDIM;
  bf16x8 qf[8];
#pragma unroll
  for (int ks = 0; ks < 8; ++ks) qf[ks] = *(const bf16x8*)(Qg + ks * 32 + lg * 8);

  floatx4 accY[16];
#pragma unroll
  for (int i = 0; i < 16; ++i) accY[i] = (floatx4){0.f, 0.f, 0.f, 0.f};
  float rsum = 0.f;

  const int qglob = qt * 64 + wq * 16 + l15;
  const int qmaxw = qt * 64 + wq * 16 + 15;
  const int nst = 2 * qt + 2;
  const int fps = (l15 ^ (l15 >> 2)) & 3;      // Ps bank-spread term

  STAGE_K(0, 0);
  for (int st = 0; st < nst; ++st) {
    const int sel = st & 1;
    STAGE_V(st);
    if (st + 1 < nst) {
      STAGE_K(st + 1, sel ^ 1);
      asm volatile("s_waitcnt vmcnt(4)" ::: "memory");   // K(st) landed
    } else {
      asm volatile("s_waitcnt vmcnt(2)" ::: "memory");   // K(st) landed
    }
    __builtin_amdgcn_s_barrier();                        // K visible
    __builtin_amdgcn_sched_barrier(0);

    if (st * 32 <= qmaxw) {
      __builtin_amdgcn_s_setprio(1);
      // --- QK^T (swapped) + softcap + causal + P write ---
#pragma unroll
      for (int stile = 0; stile < 2; ++stile) {
        floatx4 sa0 = (floatx4){0.f, 0.f, 0.f, 0.f};
        floatx4 sa1 = (floatx4){0.f, 0.f, 0.f, 0.f};
#pragma unroll
        for (int ks = 0; ks < 8; ++ks) {
          int row = (stile << 4) + l15;
          int c = (ks << 2) + lg;
          bf16x8 kf = *(const bf16x8*)((const char*)Ks2[sel] +
                        row * 512 + ((c ^ (row & 7)) << 4));
          if (ks & 1)
            sa1 = __builtin_amdgcn_mfma_f32_16x16x32_bf16(kf, qf[ks], sa1, 0, 0, 0);
          else
            sa0 = __builtin_amdgcn_mfma_f32_16x16x32_bf16(kf, qf[ks], sa0, 0, 0, 0);
        }
        int sbase = st * 32 + (stile << 4) + (lg << 2);
        float p[4];
#pragma unroll
        for (int r = 0; r < 4; ++r) {
          float s = sa0[r] + sa1[r];
          float tt = fmaf(s * s, -5.2083333e-7f, 1.0f);   // 1 - z^2/7500
          float pv = fexp2(s * 0.0901684403f * tt);       // exp2(cap*log2e)
          pv = (sbase + r <= qglob) ? pv : 0.0f;
          p[r] = pv;
          rsum += pv;
        }
        uint2 pw;
        pw.x = cvt2bf(p[0], p[1]);
        pw.y = cvt2bf(p[2], p[3]);
        int o = (stile << 5) + (lg << 3);
        int gran = (o >> 4) ^ fps;
        *(uint2*)((char*)Ps + (w << 10) + l15 * 64 + (gran << 4) + (o & 15)) = pw;
      }
      __builtin_amdgcn_s_setprio(0);
    }

    if (st + 1 < nst)
      asm volatile("s_waitcnt vmcnt(2)" ::: "memory");    // V(st) landed
    else
      asm volatile("s_waitcnt vmcnt(0)" ::: "memory");
    __builtin_amdgcn_s_barrier();                         // V visible
    __builtin_amdgcn_sched_barrier(0);

    if (st * 32 <= qmaxw) {
      __builtin_amdgcn_s_setprio(1);
      // --- PV ---
      bf16x8 pf = *(const bf16x8*)((const char*)Ps + (w << 10) + l15 * 64 +
                    ((lg ^ fps) << 4));
#pragma unroll
      for (int dt = 0; dt < 16; ++dt) {
        int row = (dt << 4) + l15;
        bf16x8 vf = *(const bf16x8*)((const char*)Vs +
                      row * 64 + ((lg ^ ((row >> 2) & 3)) << 4));
        accY[dt] = __builtin_amdgcn_mfma_f32_16x16x32_bf16(pf, vf, accY[dt], 0, 0, 0);
      }
      __builtin_amdgcn_s_setprio(0);
    }
    __builtin_amdgcn_s_barrier();   // PV done before next V overwrite
  }

  rsum += __shfl_xor(rsum, 16);
  rsum += __shfl_xor(rsum, 32);
  if (lane < 16) Ls[w][l15] = rsum;
  __syncthreads();
  float inv[4];
#pragma unroll
  for (int r = 0; r < 4; ++r) inv[r] = 1.0f / Ls[w][(lg << 2) + r];

  u16* Yg = Y + ((size_t)(b * TSEQ + qt * 64 + wq * 16)) * (NHD * HDIM) + h * HDIM;
#pragma unroll
  for (int dt = 0; dt < 16; ++dt)
#pragma unroll
    for (int r = 0; r < 4; ++r)
      Yg[(size_t)((lg << 2) + r) * (NHD * HDIM) + (dt << 4) + l15] =
          f2bf(accY[dt][r] * inv[r]);
}

// ---------------------------------------------------------------------------
extern "C" void kernel_launch(void* const* d_in, const int* in_sizes, int n_in,
                              void* d_out, int out_size, void* d_ws, size_t ws_size,
                              hipStream_t stream) {
  const float* X  = (const float*)d_in[0];
  const float* Wq = (const float*)d_in[1];
  const float* Wk = (const float*)d_in[2];
  const float* Wv = (const float*)d_in[3];
  const float* Wo = (const float*)d_in[4];
  float* out = (float*)d_out;

  u16* ws = (u16*)d_ws;
  dim3 blk(256);

  if (ws_size >= (size_t)134217728) {
    // extended layout: Wo^T folded into prep (5 launches total)
    u16* XB   = ws;                  // 8,388,608
    u16* WqT  = ws + 8388608;        // 8,388,608
    u16* WkvT = ws + 16777216;       // 8,388,608
    u16* Qb   = ws + 25165824;       // 16,777,216
    u16* KVb  = ws + 41943040;       // 16,777,216
    u16* WoT  = ws + 58720256;       // 8,388,608
    u16* Yb   = ws;                  // over XB+WqT (dead by then)

    prep_k<<<dim3(10240), blk, 0, stream>>>(X, Wq, Wk, Wv, Wo, XB, WqT, WkvT, WoT);
    gemm256_k<1, 256><<<dim3(256), dim3(512), 0, stream>>>(XB, WqT,  Qb,  4096, 4096, 2048);
    gemm256_k<3, 256><<<dim3(256), dim3(512), 0, stream>>>(XB, WkvT, KVb, 4096, 4096, 2048);
    attn_k<<<dim3(16, 32), dim3(512), 0, stream>>>(Qb, KVb, KVb + 8388608, Yb);
    gemm256_k<0, 128><<<dim3(256), dim3(512), 0, stream>>>(Yb, WoT, out, 4096, 2048, 4096);
  } else if (ws_size >= (size_t)117440512) {
    u16* XB   = ws;                  // 8,388,608
    u16* WqT  = ws + 8388608;        // 8,388,608
    u16* WkvT = ws + 16777216;       // 8,388,608
    u16* Qb   = ws + 25165824;       // 16,777,216
    u16* KVb  = ws + 41943040;       // 16,777,216
    u16* Yb   = ws;                  // over XB+WqT (dead by then)
    u16* WoT  = ws + 25165824;       // over Qb (dead after attn)

    prep_k<<<dim3(8192), blk, 0, stream>>>(X, Wq, Wk, Wv, Wo, XB, WqT, WkvT, WkvT);
    gemm256_k<1, 256><<<dim3(256), dim3(512), 0, stream>>>(XB, WqT,  Qb,  4096, 4096, 2048);
    gemm256_k<3, 256><<<dim3(256), dim3(512), 0, stream>>>(XB, WkvT, KVb, 4096, 4096, 2048);
    attn_k<<<dim3(16, 32), dim3(512), 0, stream>>>(Qb, KVb, KVb + 8388608, Yb);
    tconv_k<<<dim3(32, 64), blk, 0, stream>>>(Wo, WoT, 4096, 2048);
    gemm256_k<0, 128><<<dim3(256), dim3(512), 0, stream>>>(Yb, WoT, out, 4096, 2048, 4096);
  } else {
    u16* XB   = ws;                  // 8,388,608
    u16* WT   = ws + 8388608;        // 8,388,608 (WqT then WkvT, sequential)
    u16* Qb   = ws + 16777216;       // 16,777,216
    u16* KVb  = ws + 33554432;       // 16,777,216
    u16* Yb   = ws;                  // over XB+WT
    u16* WoT  = ws + 16777216;       // over Qb

    xconv_k<<<dim3(4096), blk, 0, stream>>>(X, XB);
    tconv_k<<<dim3(64, 32), blk, 0, stream>>>(Wq, WT, 2048, 4096);
    gemm256_k<1, 256><<<dim3(256), dim3(512), 0, stream>>>(XB, WT, Qb, 4096, 4096, 2048);
    tconv_k<<<dim3(32, 32), blk, 0, stream>>>(Wk, WT, 2048, 2048);
    tconv_k<<<dim3(32, 32), blk, 0, stream>>>(Wv, WT + (size_t)2048 * 2048, 2048, 2048);
    gemm256_k<3, 256><<<dim3(256), dim3(512), 0, stream>>>(XB, WT, KVb, 4096, 4096, 2048);
    attn_k<<<dim3(16, 32), dim3(512), 0, stream>>>(Qb, KVb, KVb + 8388608, Yb);
    tconv_k<<<dim3(32, 64), blk, 0, stream>>>(Wo, WoT, 4096, 2048);
    gemm256_k<0, 128><<<dim3(256), dim3(512), 0, stream>>>(Yb, WoT, out, 4096, 2048, 4096);
  }
}

// Round 21
// 392.505 us; speedup vs baseline: 1.0426x; 1.0022x over previous
//
#include <hip/hip_runtime.h>
#include <hip/hip_bf16.h>

#define NHD 16          // NH
#define NKVH 8          // NKV
#define HDIM 256        // HD
#define TSEQ 2048       // T
#define BATCH 2         // B

typedef unsigned int   u32;
typedef unsigned short u16;

typedef __attribute__((ext_vector_type(8))) short bf16x8;
typedef __attribute__((ext_vector_type(4))) float floatx4;

__device__ inline u32 cvt2bf(float lo, float hi) {
  u32 r;
  asm("v_cvt_pk_bf16_f32 %0, %1, %2" : "=v"(r) : "v"(lo), "v"(hi));
  return r;
}
__device__ inline u16 f2bf(float f) {
  union { float f; u32 i; } v; v.f = f;
  u32 r = v.i + 0x7fffu + ((v.i >> 16) & 1u);
  return (u16)(r >> 16);
}
__device__ inline float bf2f(u16 u) {
  union { u32 i; float f; } v; v.i = ((u32)u) << 16; return v.f;
}
__device__ inline float fexp2(float x) {
  float r; asm("v_exp_f32 %0, %1" : "=v"(r) : "v"(x)); return r;
}
__device__ inline float fsin(float x) {
  float r; asm("v_sin_f32 %0, %1" : "=v"(r) : "v"(x)); return r;
}
__device__ inline float fcos(float x) {
  float r; asm("v_cos_f32 %0, %1" : "=v"(r) : "v"(x)); return r;
}
__device__ inline float ffract(float x) {
  float r; asm("v_fract_f32 %0, %1" : "=v"(r) : "v"(x)); return r;
}

typedef const __attribute__((address_space(1))) u32* gptr_t;
typedef __attribute__((address_space(3))) u32* lptr_t;
__device__ inline void gl_lds16(const void* g, void* l) {
  __builtin_amdgcn_global_load_lds((gptr_t)g, (lptr_t)l, 16, 0, 0);
}

// ---------------------------------------------------------------------------
// Transpose+convert body: fp32 in[R][Cc] -> bf16 out[Cc][R], 64x64 tile (bx,by)
// ---------------------------------------------------------------------------
__device__ inline void tconv_body(const float* __restrict__ in,
                                  u16* __restrict__ out, int R, int Cc,
                                  int bx, int by, int tid) {
  __shared__ float tile[64][65];
  const int r0 = by * 64, c0 = bx * 64;
  const int tr = tid >> 4;
  const int tc = (tid & 15) * 4;
#pragma unroll
  for (int j = 0; j < 4; ++j) {
    float4 v = *(const float4*)(in + (size_t)(r0 + tr + j * 16) * Cc + c0 + tc);
    tile[tr + j * 16][tc + 0] = v.x;
    tile[tr + j * 16][tc + 1] = v.y;
    tile[tr + j * 16][tc + 2] = v.z;
    tile[tr + j * 16][tc + 3] = v.w;
  }
  __syncthreads();
#pragma unroll
  for (int j = 0; j < 4; ++j) {
    int c = tr + j * 16;
    u16 o[4];
#pragma unroll
    for (int i = 0; i < 4; ++i) o[i] = f2bf(tile[tc + i][c]);
    *(uint2*)(out + (size_t)(c0 + c) * R + r0 + tc) = *(const uint2*)o;
  }
}

__global__ __launch_bounds__(256) void tconv_k(
    const float* __restrict__ in, u16* __restrict__ out, int R, int Cc)
{
  tconv_body(in, out, R, Cc, blockIdx.x, blockIdx.y, threadIdx.x);
}

__global__ __launch_bounds__(256) void xconv_k(
    const float* __restrict__ in, u16* __restrict__ out)
{
  size_t i = (size_t)blockIdx.x * 256 + threadIdx.x;
  float4 a = *(const float4*)(in + i * 8);
  float4 b = *(const float4*)(in + i * 8 + 4);
  uint4 o;
  o.x = cvt2bf(a.x, a.y); o.y = cvt2bf(a.z, a.w);
  o.z = cvt2bf(b.x, b.y); o.w = cvt2bf(b.z, b.w);
  *(uint4*)(out + i * 8) = o;
}

// ---------------------------------------------------------------------------
// Merged prep: X cvt + Wq^T + Wk^T + Wv^T (+ Wo^T when grid = 10240).
// ---------------------------------------------------------------------------
__global__ __launch_bounds__(256) void prep_k(
    const float* __restrict__ X,  const float* __restrict__ Wq,
    const float* __restrict__ Wk, const float* __restrict__ Wv,
    const float* __restrict__ Wo,
    u16* __restrict__ XB, u16* __restrict__ WqT, u16* __restrict__ WkvT,
    u16* __restrict__ WoT)
{
  const int bid = blockIdx.x, tid = threadIdx.x;
  if (bid < 4096) {
    size_t i = (size_t)bid * 256 + tid;
    float4 a = *(const float4*)(X + i * 8);
    float4 b = *(const float4*)(X + i * 8 + 4);
    uint4 o;
    o.x = cvt2bf(a.x, a.y); o.y = cvt2bf(a.z, a.w);
    o.z = cvt2bf(b.x, b.y); o.w = cvt2bf(b.z, b.w);
    *(uint4*)(XB + i * 8) = o;
  } else if (bid < 6144) {
    int idx = bid - 4096;
    tconv_body(Wq, WqT, 2048, 4096, idx & 63, idx >> 6, tid);
  } else if (bid < 7168) {
    int idx = bid - 6144;
    tconv_body(Wk, WkvT, 2048, 2048, idx & 31, idx >> 5, tid);
  } else if (bid < 8192) {
    int idx = bid - 7168;
    tconv_body(Wv, WkvT + (size_t)2048 * 2048, 2048, 2048, idx & 31, idx >> 5, tid);
  } else {
    int idx = bid - 8192;
    tconv_body(Wo, WoT, 4096, 2048, idx & 31, idx >> 5, tid);
  }
}

// ---------------------------------------------------------------------------
// R5-proven 2-phase GEMM + FUSED ROPE EPILOGUE.
// EPI 0: fp32 [M][N].  EPI 1: Q roped.  EPI 3: fused KV (K roped + V^T).
// EPI 5: fully fused QKV (N=8192): n<4096 Q roped -> Op; 4096..6143 K roped
// -> Op+16777216; >=6144 V^T plain -> Op+16777216+8388608.
// ---------------------------------------------------------------------------
template<int EPI, int BM>
__global__ __launch_bounds__(512, 2) void gemm256_k(
    const u16* __restrict__ Ab, const u16* __restrict__ BTp,
    void* __restrict__ Op, int M, int N, int K)
{
  constexpr int NI = BM / 32;
  constexpr int AI = BM / 64;
  __shared__ u16 LA[2][BM * 64];
  __shared__ u16 LB[2][256 * 64];
  const int t = threadIdx.x;
  const int lane = t & 63, wave = t >> 6;
  const int lg = lane >> 4, l15 = lane & 15;
  const int wm = wave >> 2, wn = wave & 3;
  const int mtiles = M / BM;
  const int mt = (int)blockIdx.x % mtiles, nt = (int)blockIdx.x / mtiles;
  const int m0 = mt * BM, n0 = nt << 8;

  const int arow = wave * (BM / 8) + (lane >> 3);
  const int ska  = ((lane & 7) ^ (arow & 7)) << 3;
  const int brow = wave * 32 + (lane >> 3);
  const int skb  = ((lane & 7) ^ (brow & 7)) << 3;
  const u16* Ag = Ab  + (size_t)(m0 + arow) * K + ska;
  const u16* Bg = BTp + (size_t)(n0 + brow) * K + skb;

  auto STAGE = [&](int k0, int sel) {
#pragma unroll
    for (int q = 0; q < AI; ++q)
      gl_lds16(Ag + k0 + (size_t)q * 8 * K, &LA[sel][(wave * (BM / 8) + q * 8) * 64]);
#pragma unroll
    for (int q = 0; q < 4; ++q)
      gl_lds16(Bg + k0 + (size_t)q * 8 * K, &LB[sel][(wave * 32 + q * 8) * 64]);
  };

  floatx4 acc[NI][4];
#pragma unroll
  for (int i = 0; i < NI; ++i)
#pragma unroll
    for (int j = 0; j < 4; ++j) acc[i][j] = (floatx4){0.f, 0.f, 0.f, 0.f};

  STAGE(0, 0);
  const int KT = K >> 6;
  for (int kt = 0; kt < KT; ++kt) {
    const int sel = kt & 1;
    if (kt + 1 < KT) {
      STAGE((kt + 1) << 6, sel ^ 1);
      if constexpr (BM == 256) asm volatile("s_waitcnt vmcnt(8)" ::: "memory");
      else                     asm volatile("s_waitcnt vmcnt(6)" ::: "memory");
    } else {
      asm volatile("s_waitcnt vmcnt(0)" ::: "memory");
    }
    __builtin_amdgcn_s_barrier();
    __builtin_amdgcn_sched_barrier(0);
    __builtin_amdgcn_s_setprio(1);
#pragma unroll
    for (int ks = 0; ks < 2; ++ks) {
      const int c = (ks << 2) + lg;
      bf16x8 bfv[4];
#pragma unroll
      for (int j = 0; j < 4; ++j) {
        int row = (EPI == 0) ? (wn * 64 + (j << 4) + l15)
                             : (wn * 32 + ((j & 1) << 4) + ((j >> 1) << 7) + l15);
        bfv[j] = *(const bf16x8*)(&LB[sel][row * 64 + ((c ^ (row & 7)) << 3)]);
      }
#pragma unroll
      for (int i = 0; i < NI; ++i) {
        int row = wm * (BM / 2) + (i << 4) + l15;
        bf16x8 af = *(const bf16x8*)(&LA[sel][row * 64 + ((c ^ (row & 7)) << 3)]);
#pragma unroll
        for (int j = 0; j < 4; ++j)
          acc[i][j] = __builtin_amdgcn_mfma_f32_16x16x32_bf16(af, bfv[j], acc[i][j], 0, 0, 0);
      }
    }
    __builtin_amdgcn_s_setprio(0);
    __builtin_amdgcn_s_barrier();
  }

  if constexpr (EPI == 0) {
#pragma unroll
    for (int i = 0; i < NI; ++i)
#pragma unroll
      for (int j = 0; j < 4; ++j)
#pragma unroll
        for (int r = 0; r < 4; ++r) {
          int m = m0 + wm * (BM / 2) + (i << 4) + (lg << 2) + r;
          int n = n0 + wn * 64 + (j << 4) + l15;
          ((float*)Op)[(size_t)m * N + n] = acc[i][j][r];
        }
  } else {
    float invf2[2];
#pragma unroll
    for (int j = 0; j < 2; ++j) {
      int col = wn * 32 + (j << 4) + l15;
      invf2[j] = fexp2(fmaf(-(float)col, 0.103810253f, -2.651496129f));
    }
#pragma unroll
    for (int i = 0; i < NI; ++i) {
#pragma unroll
      for (int j = 0; j < 2; ++j) {
        int col = wn * 32 + (j << 4) + l15;
        int n_lo = n0 + col;
#pragma unroll
        for (int r = 0; r < 4; ++r) {
          int m = m0 + wm * (BM / 2) + (i << 4) + (lg << 2) + r;
          int bb = m >> 11, tt = m & 2047;
          float vlo = acc[i][j][r], vhi = acc[i][j + 2][r];
          bool rope;
          if (EPI == 1)      rope = true;
          else if (EPI == 3) rope = (n_lo < 2048);
          else               rope = (n_lo < 6144);   // EPI 5: Q and K regions
          if (rope) {
            float rev = ffract((float)tt * invf2[j]);
            float sn = fsin(rev), cs = fcos(rev);
            float olo = vlo * cs - vhi * sn;
            float ohi = vhi * cs + vlo * sn;
            vlo = olo; vhi = ohi;
          }
          if (EPI == 1) {
            int h = n_lo >> 8;
            u16* dst = (u16*)Op + (((size_t)bb * NHD + h) * TSEQ + tt) * HDIM + col;
            dst[0]   = f2bf(vlo);
            dst[128] = f2bf(vhi);
          } else if (EPI == 3) {
            if (n_lo < 2048) {
              int h = n_lo >> 8;
              u16* dst = (u16*)Op + (((size_t)bb * NKVH + h) * TSEQ + tt) * HDIM + col;
              dst[0]   = f2bf(vlo);
              dst[128] = f2bf(vhi);
            } else {
              int n2 = n_lo - 2048;
              int h = n2 >> 8;
              u16* dst = (u16*)Op + 8388608u +
                         (((size_t)bb * NKVH + h) * HDIM + col) * TSEQ + tt;
              dst[0] = f2bf(vlo);
              dst[(size_t)128 * TSEQ] = f2bf(vhi);
            }
          } else {   // EPI 5
            if (n_lo < 4096) {                       // Q
              int h = n_lo >> 8;
              u16* dst = (u16*)Op + (((size_t)bb * NHD + h) * TSEQ + tt) * HDIM + col;
              dst[0]   = f2bf(vlo);
              dst[128] = f2bf(vhi);
            } else if (n_lo < 6144) {                // K
              int h = (n_lo - 4096) >> 8;
              u16* dst = (u16*)Op + 16777216u +
                         (((size_t)bb * NKVH + h) * TSEQ + tt) * HDIM + col;
              dst[0]   = f2bf(vlo);
              dst[128] = f2bf(vhi);
            } else {                                 // V^T
              int n2 = n_lo - 6144;
              int h = n2 >> 8;
              u16* dst = (u16*)Op + 16777216u + 8388608u +
                         (((size_t)bb * NKVH + h) * HDIM + col) * TSEQ + tt;
              dst[0] = f2bf(vlo);
              dst[(size_t)128 * TSEQ] = f2bf(vhi);
            }
          }
        }
      }
    }
  }
}

// ---------------------------------------------------------------------------
// Causal flash attention (R18 winner, verbatim): GQA-pair block (512 thr,
// waves 0-3 head 2hkv, 4-7 head 2hkv+1, shared K/V), K dbuf + V single via
// gl_lds, 2 K + 2 V chunks per thread.
// Iter: STAGE_V(st); STAGE_K(st+1); vmcnt(4) -> bar -> QK -> vmcnt(2) ->
// bar -> PV -> bar.  Tail: 2/0.  LDS 56.5 KB -> 2 blocks/CU = 16 waves.
// Grid: x=(hkv,b)=16, y=qt descending (LPT).
// ---------------------------------------------------------------------------
__global__ __launch_bounds__(512, 2) void attn_k(
    const u16* __restrict__ Q, const u16* __restrict__ Kb,
    const u16* __restrict__ Vt, u16* __restrict__ Y)
{
  __shared__ u16 Ks2[2][32 * 256];   // 32 KB, [s][d] 512B rows, src-swizzled
  __shared__ u16 Vs[256 * 32];       // 16 KB, [d][s] 64B rows, src-swizzled
  __shared__ u16 Ps[8 * 16 * 32];    // 8 KB, per-wave [q16][s32]
  __shared__ float Ls[8][16];
  const int t = threadIdx.x, lane = t & 63, w = t >> 6;   // w in 0..7
  const int lg = lane >> 4, l15 = lane & 15;
  const int hq = w >> 2, wq = w & 3;                      // head-half, q-group
  const int qt = 31 - (int)blockIdx.y;                    // big blocks first
  const int hkv = (int)blockIdx.x >> 1, b = (int)blockIdx.x & 1;
  const int h = 2 * hkv + hq;

  const u16* Kg = Kb + ((size_t)(b * NKVH + hkv)) * TSEQ * HDIM;  // [s][d]
  const u16* Vg = Vt + ((size_t)(b * NKVH + hkv)) * HDIM * TSEQ;  // [d][s]

  int koff[2], voff[2];
#pragma unroll
  for (int q = 0; q < 2; ++q) {
    int krow = w * 4 + q * 2 + (lane >> 5);
    int kcc  = lane & 31;
    koff[q] = krow * 256 + ((kcc ^ (krow & 7)) << 3);
    int vd  = w * 32 + q * 16 + (lane >> 2);
    voff[q] = vd * TSEQ + (((lane & 3) ^ ((vd >> 2) & 3)) << 3);
  }

  auto STAGE_K = [&](int st, int sel) {
    const u16* kbase = Kg + (size_t)st * (32 * 256);
#pragma unroll
    for (int q = 0; q < 2; ++q)
      gl_lds16(kbase + koff[q], &Ks2[sel][(w * 4 + q * 2) * 256]);
  };
  auto STAGE_V = [&](int st) {
    const u16* vbase = Vg + st * 32;
#pragma unroll
    for (int q = 0; q < 2; ++q)
      gl_lds16(vbase + voff[q], &Vs[(w * 32 + q * 16) * 32]);
  };

  const u16* Qg = Q + (((size_t)(b * NHD + h)) * TSEQ + qt * 64 + wq * 16 + l15) * HDIM;
  bf16x8 qf[8];
#pragma unroll
  for (int ks = 0; ks < 8; ++ks) qf[ks] = *(const bf16x8*)(Qg + ks * 32 + lg * 8);

  floatx4 accY[16];
#pragma unroll
  for (int i = 0; i < 16; ++i) accY[i] = (floatx4){0.f, 0.f, 0.f, 0.f};
  float rsum = 0.f;

  const int qglob = qt * 64 + wq * 16 + l15;
  const int qmaxw = qt * 64 + wq * 16 + 15;
  const int nst = 2 * qt + 2;
  const int fps = (l15 ^ (l15 >> 2)) & 3;      // Ps bank-spread term

  STAGE_K(0, 0);
  for (int st = 0; st < nst; ++st) {
    const int sel = st & 1;
    STAGE_V(st);
    if (st + 1 < nst) {
      STAGE_K(st + 1, sel ^ 1);
      asm volatile("s_waitcnt vmcnt(4)" ::: "memory");   // K(st) landed
    } else {
      asm volatile("s_waitcnt vmcnt(2)" ::: "memory");   // K(st) landed
    }
    __builtin_amdgcn_s_barrier();                        // K visible
    __builtin_amdgcn_sched_barrier(0);

    if (st * 32 <= qmaxw) {
      __builtin_amdgcn_s_setprio(1);
      // --- QK^T (swapped) + softcap + causal + P write ---
#pragma unroll
      for (int stile = 0; stile < 2; ++stile) {
        floatx4 sa0 = (floatx4){0.f, 0.f, 0.f, 0.f};
        floatx4 sa1 = (floatx4){0.f, 0.f, 0.f, 0.f};
#pragma unroll
        for (int ks = 0; ks < 8; ++ks) {
          int row = (stile << 4) + l15;
          int c = (ks << 2) + lg;
          bf16x8 kf = *(const bf16x8*)((const char*)Ks2[sel] +
                        row * 512 + ((c ^ (row & 7)) << 4));
          if (ks & 1)
            sa1 = __builtin_amdgcn_mfma_f32_16x16x32_bf16(kf, qf[ks], sa1, 0, 0, 0);
          else
            sa0 = __builtin_amdgcn_mfma_f32_16x16x32_bf16(kf, qf[ks], sa0, 0, 0, 0);
        }
        int sbase = st * 32 + (stile << 4) + (lg << 2);
        float p[4];
#pragma unroll
        for (int r = 0; r < 4; ++r) {
          float s = sa0[r] + sa1[r];
          float tt = fmaf(s * s, -5.2083333e-7f, 1.0f);   // 1 - z^2/7500
          float pv = fexp2(s * 0.0901684403f * tt);       // exp2(cap*log2e)
          pv = (sbase + r <= qglob) ? pv : 0.0f;
          p[r] = pv;
          rsum += pv;
        }
        uint2 pw;
        pw.x = cvt2bf(p[0], p[1]);
        pw.y = cvt2bf(p[2], p[3]);
        int o = (stile << 5) + (lg << 3);
        int gran = (o >> 4) ^ fps;
        *(uint2*)((char*)Ps + (w << 10) + l15 * 64 + (gran << 4) + (o & 15)) = pw;
      }
      __builtin_amdgcn_s_setprio(0);
    }

    if (st + 1 < nst)
      asm volatile("s_waitcnt vmcnt(2)" ::: "memory");    // V(st) landed
    else
      asm volatile("s_waitcnt vmcnt(0)" ::: "memory");
    __builtin_amdgcn_s_barrier();                         // V visible
    __builtin_amdgcn_sched_barrier(0);

    if (st * 32 <= qmaxw) {
      __builtin_amdgcn_s_setprio(1);
      // --- PV ---
      bf16x8 pf = *(const bf16x8*)((const char*)Ps + (w << 10) + l15 * 64 +
                    ((lg ^ fps) << 4));
#pragma unroll
      for (int dt = 0; dt < 16; ++dt) {
        int row = (dt << 4) + l15;
        bf16x8 vf = *(const bf16x8*)((const char*)Vs +
                      row * 64 + ((lg ^ ((row >> 2) & 3)) << 4));
        accY[dt] = __builtin_amdgcn_mfma_f32_16x16x32_bf16(pf, vf, accY[dt], 0, 0, 0);
      }
      __builtin_amdgcn_s_setprio(0);
    }
    __builtin_amdgcn_s_barrier();   // PV done before next V overwrite
  }

  rsum += __shfl_xor(rsum, 16);
  rsum += __shfl_xor(rsum, 32);
  if (lane < 16) Ls[w][l15] = rsum;
  __syncthreads();
  float inv[4];
#pragma unroll
  for (int r = 0; r < 4; ++r) inv[r] = 1.0f / Ls[w][(lg << 2) + r];

  u16* Yg = Y + ((size_t)(b * TSEQ + qt * 64 + wq * 16)) * (NHD * HDIM) + h * HDIM;
#pragma unroll
  for (int dt = 0; dt < 16; ++dt)
#pragma unroll
    for (int r = 0; r < 4; ++r)
      Yg[(size_t)((lg << 2) + r) * (NHD * HDIM) + (dt << 4) + l15] =
          f2bf(accY[dt][r] * inv[r]);
}

// ---------------------------------------------------------------------------
extern "C" void kernel_launch(void* const* d_in, const int* in_sizes, int n_in,
                              void* d_out, int out_size, void* d_ws, size_t ws_size,
                              hipStream_t stream) {
  const float* X  = (const float*)d_in[0];
  const float* Wq = (const float*)d_in[1];
  const float* Wk = (const float*)d_in[2];
  const float* Wv = (const float*)d_in[3];
  const float* Wo = (const float*)d_in[4];
  float* out = (float*)d_out;

  u16* ws = (u16*)d_ws;
  dim3 blk(256);

  if (ws_size >= (size_t)134217728) {
    // extended layout: 4 launches total.  WqT+WkvT contiguous [8192][2048];
    // Qb and KVb contiguous (+16,777,216 elements).
    u16* XB   = ws;                  // 8,388,608
    u16* WqT  = ws + 8388608;        // 8,388,608  (Wq^T)
    u16* WkvT = ws + 16777216;       // 8,388,608  (Wk^T | Wv^T)
    u16* Qb   = ws + 25165824;       // 16,777,216
    u16* KVb  = ws + 41943040;       // 16,777,216 (= Qb + 16777216)
    u16* WoT  = ws + 58720256;       // 8,388,608
    u16* Yb   = ws;                  // over XB+WqT (dead by then)

    prep_k<<<dim3(10240), blk, 0, stream>>>(X, Wq, Wk, Wv, Wo, XB, WqT, WkvT, WoT);
    gemm256_k<5, 256><<<dim3(512), dim3(512), 0, stream>>>(XB, WqT, Qb, 4096, 8192, 2048);
    attn_k<<<dim3(16, 32), dim3(512), 0, stream>>>(Qb, KVb, KVb + 8388608, Yb);
    gemm256_k<0, 128><<<dim3(256), dim3(512), 0, stream>>>(Yb, WoT, out, 4096, 2048, 4096);
  } else if (ws_size >= (size_t)117440512) {
    u16* XB   = ws;                  // 8,388,608
    u16* WqT  = ws + 8388608;        // 8,388,608
    u16* WkvT = ws + 16777216;       // 8,388,608
    u16* Qb   = ws + 25165824;       // 16,777,216
    u16* KVb  = ws + 41943040;       // 16,777,216
    u16* Yb   = ws;                  // over XB+WqT (dead by then)
    u16* WoT  = ws + 25165824;       // over Qb (dead after attn)

    prep_k<<<dim3(8192), blk, 0, stream>>>(X, Wq, Wk, Wv, Wo, XB, WqT, WkvT, WkvT);
    gemm256_k<1, 256><<<dim3(256), dim3(512), 0, stream>>>(XB, WqT,  Qb,  4096, 4096, 2048);
    gemm256_k<3, 256><<<dim3(256), dim3(512), 0, stream>>>(XB, WkvT, KVb, 4096, 4096, 2048);
    attn_k<<<dim3(16, 32), dim3(512), 0, stream>>>(Qb, KVb, KVb + 8388608, Yb);
    tconv_k<<<dim3(32, 64), blk, 0, stream>>>(Wo, WoT, 4096, 2048);
    gemm256_k<0, 128><<<dim3(256), dim3(512), 0, stream>>>(Yb, WoT, out, 4096, 2048, 4096);
  } else {
    u16* XB   = ws;                  // 8,388,608
    u16* WT   = ws + 8388608;        // 8,388,608 (WqT then WkvT, sequential)
    u16* Qb   = ws + 16777216;       // 16,777,216
    u16* KVb  = ws + 33554432;       // 16,777,216
    u16* Yb   = ws;                  // over XB+WT
    u16* WoT  = ws + 16777216;       // over Qb

    xconv_k<<<dim3(4096), blk, 0, stream>>>(X, XB);
    tconv_k<<<dim3(64, 32), blk, 0, stream>>>(Wq, WT, 2048, 4096);
    gemm256_k<1, 256><<<dim3(256), dim3(512), 0, stream>>>(XB, WT, Qb, 4096, 4096, 2048);
    tconv_k<<<dim3(32, 32), blk, 0, stream>>>(Wk, WT, 2048, 2048);
    tconv_k<<<dim3(32, 32), blk, 0, stream>>>(Wv, WT + (size_t)2048 * 2048, 2048, 2048);
    gemm256_k<3, 256><<<dim3(256), dim3(512), 0, stream>>>(XB, WT, KVb, 4096, 4096, 2048);
    attn_k<<<dim3(16, 32), dim3(512), 0, stream>>>(Qb, KVb, KVb + 8388608, Yb);
    tconv_k<<<dim3(32, 64), blk, 0, stream>>>(Wo, WoT, 4096, 2048);
    gemm256_k<0, 128><<<dim3(256), dim3(512), 0, stream>>>(Yb, WoT, out, 4096, 2048, 4096);
  }
}